// Round 3
// baseline (432.686 us; speedup 1.0000x reference)
//
#include <hip/hip_runtime.h>
#include <hip/hip_bf16.h>

// RK4 Gray-Scott, fused single kernel. Conflict-free LDS mapping:
// every 16-lane phase of a ds_read_b128 reads 256B contiguous from ONE row.
// Lane mapping per stage loop: g = i & 15 (x-group of 4 floats), row = i >> 4.
// Out-of-region groups clamp g (broadcast reads, free) and mask writes.
//
// Layouts (physical col p, all quad accesses 16B-aligned):
//   A  (u0,v0):  p = x + 4, stride 68, rows 56   (logical x,y in [0,56))
//   B  (Y1/Y3):  p = x,     stride 60, rows 50   (row = y - 3)
//   C  (Y2):     p = x - 4, stride 52, rows 44   (row = y - 6)
//   ACC:         p = x - 12,stride 32, rows 32   (row = y - 12)

#define TS   32
#define RAD  12
#define ASTR 68
#define BSTR 60
#define CSTR 52
#define WSTR 32

#define W0 ((-980.0f / 1e-4f) / 180.0f)
#define W1 ((  270.0f / 1e-4f) / 180.0f)
#define W2 (( -27.0f / 1e-4f) / 180.0f)
#define W3 ((   2.0f / 1e-4f) / 180.0f)

__device__ __forceinline__ float4 f4_add(float4 a, float4 b) {
    return make_float4(a.x + b.x, a.y + b.y, a.z + b.z, a.w + b.w);
}
__device__ __forceinline__ float4 f4_fma(float s, float4 a, float4 b) {
    return make_float4(fmaf(s, a.x, b.x), fmaf(s, a.y, b.y),
                       fmaf(s, a.z, b.z), fmaf(s, a.w, b.w));
}
__device__ __forceinline__ float4 f4_mul(float s, float4 a) {
    return make_float4(s * a.x, s * a.y, s * a.z, s * a.w);
}
__device__ __forceinline__ float el(const float4& v, int j) { return (&v.x)[j]; }
__device__ __forceinline__ float& elr(float4& v, int j) { return (&v.x)[j]; }

__device__ __forceinline__ void lap4(const float* __restrict__ base, int ry, int p0,
                                     int stride, float4& lap, float4& ctr)
{
    const float* row = base + ry * stride;
    float4 c0 = *(const float4*)(row + p0 - 4);
    float4 c1 = *(const float4*)(row + p0);
    float4 c2 = *(const float4*)(row + p0 + 4);
    float4 n1 = *(const float4*)(base + (ry - 1) * stride + p0);
    float4 s1 = *(const float4*)(base + (ry + 1) * stride + p0);
    float4 n2 = *(const float4*)(base + (ry - 2) * stride + p0);
    float4 s2 = *(const float4*)(base + (ry + 2) * stride + p0);
    float4 n3 = *(const float4*)(base + (ry - 3) * stride + p0);
    float4 s3 = *(const float4*)(base + (ry + 3) * stride + p0);

    float4 vp = f4_fma(W1, f4_add(n1, s1),
                f4_fma(W2, f4_add(n2, s2),
                f4_mul(W3, f4_add(n3, s3))));

    float r[12] = { c0.x, c0.y, c0.z, c0.w,
                    c1.x, c1.y, c1.z, c1.w,
                    c2.x, c2.y, c2.z, c2.w };
    #pragma unroll
    for (int j = 0; j < 4; ++j) {
        float hp = fmaf(W1, r[3 + j] + r[5 + j],
                   fmaf(W2, r[2 + j] + r[6 + j],
                        W3 * (r[1 + j] + r[7 + j])));
        elr(lap, j) = fmaf(W0, r[4 + j], hp + el(vp, j));
    }
    ctr = c1;
}

__global__ __launch_bounds__(256, 2) void rcnn_rk4_fused(
    const float* __restrict__ h,
    const float* __restrict__ pCA, const float* __restrict__ pCB,
    const float* __restrict__ pNA, const float* __restrict__ pNB,
    const float* __restrict__ pf,  const float* __restrict__ pk,
    float* __restrict__ out)
{
    __shared__ __align__(16) float Au[56][ASTR], Av[56][ASTR];
    __shared__ __align__(16) float Bu[50][BSTR], Bv[50][BSTR];
    __shared__ __align__(16) float Cu[44][CSTR], Cv[44][CSTR];
    __shared__ __align__(16) float ACu[32][WSTR], ACv[32][WSTR];

    const int tid = threadIdx.x;
    const int b   = blockIdx.z;

    const float CA = pCA[0], CB = pCB[0];
    const float NA = pNA[0], NB = pNB[0];
    const float ff = pf[0],  kk = pk[0];
    const float mu_u = 4e-5f / (1.0f + expf(-CA));
    const float mu_v = 4e-5f / (1.0f + expf(-CB));
    const float kpf  = kk + ff;

    const size_t baseU = ((size_t)b * 2 + 0) * 1024 * 1024;
    const size_t baseV = baseU + 1024 * 1024;

    const int y0 = blockIdx.y * TS - RAD;
    const int xg = blockIdx.x * TS - RAD;

    // ---- load u0,v0 (56 rows x 14 quads), phase-aligned writes ----
    for (int i = tid; i < 56 * 16; i += 256) {
        int r = i >> 4, g = i & 15;
        if (g < 14) {
            int gy = (y0 + r) & 1023;
            int gx = (xg + 4 * g) & 1023;
            const size_t off = (size_t)gy * 1024 + gx;
            *(float4*)&Au[r][4 * g + 4] = *(const float4*)(h + baseU + off);
            *(float4*)&Av[r][4 * g + 4] = *(const float4*)(h + baseV + off);
        }
    }
    __syncthreads();

    // ---- stage 1: k1 over x,y in [3,53)^2 ; Y1 = u0 + 0.25 k1 -> B ----
    for (int i = tid; i < 50 * 16; i += 256) {
        int rr = i >> 4, g = i & 15;
        int gc = min(g, 13);
        int y  = rr + 3;
        int x0 = 4 * gc;
        float4 lu, cu, lv, cv;
        lap4(&Au[0][0], y, x0 + 4, ASTR, lu, cu);
        lap4(&Av[0][0], y, x0 + 4, ASTR, lv, cv);
        float4 y1u, y1v, kuq, kvq;
        #pragma unroll
        for (int j = 0; j < 4; ++j) {
            float u = el(cu, j), v = el(cv, j);
            float uv2 = u * v * v;
            float ku = fmaf(mu_u, el(lu, j), fmaf(NA, uv2, ff * (1.0f - u)));
            float kv = fmaf(mu_v, el(lv, j), fmaf(NB, uv2, -kpf * v));
            elr(y1u, j) = fmaf(0.25f, ku, u);
            elr(y1v, j) = fmaf(0.25f, kv, v);
            elr(kuq, j) = ku; elr(kvq, j) = kv;
        }
        if (g >= 1 && g <= 12) {
            *(float4*)&Bu[y - 3][x0] = y1u;
            *(float4*)&Bv[y - 3][x0] = y1v;
        } else if (g == 0) {
            Bu[y - 3][3] = el(y1u, 3); Bv[y - 3][3] = el(y1v, 3);
        } else if (g == 13) {
            Bu[y - 3][52] = el(y1u, 0); Bv[y - 3][52] = el(y1v, 0);
        }
        if (y >= 12 && y < 44 && g >= 3 && g <= 10) {
            *(float4*)&ACu[y - 12][x0 - 12] = kuq;
            *(float4*)&ACv[y - 12][x0 - 12] = kvq;
        }
    }
    __syncthreads();

    // ---- stage 2: k2 over [6,50)^2 ; Y2 = u0 + 0.25 k2 -> C ----
    for (int i = tid; i < 44 * 16; i += 256) {
        int rr = i >> 4, g = i & 15;
        int gc = min(max(g, 1), 12);
        int y  = rr + 6;
        int x0 = 4 * gc;
        float4 lu, cu, lv, cv;
        lap4(&Bu[0][0], y - 3, x0, BSTR, lu, cu);
        lap4(&Bv[0][0], y - 3, x0, BSTR, lv, cv);
        float4 au = *(const float4*)&Au[y][x0 + 4];
        float4 av = *(const float4*)&Av[y][x0 + 4];
        float4 y2u, y2v, kuq, kvq;
        #pragma unroll
        for (int j = 0; j < 4; ++j) {
            float u = el(cu, j), v = el(cv, j);
            float uv2 = u * v * v;
            float ku = fmaf(mu_u, el(lu, j), fmaf(NA, uv2, ff * (1.0f - u)));
            float kv = fmaf(mu_v, el(lv, j), fmaf(NB, uv2, -kpf * v));
            elr(y2u, j) = fmaf(0.25f, ku, el(au, j));
            elr(y2v, j) = fmaf(0.25f, kv, el(av, j));
            elr(kuq, j) = ku; elr(kvq, j) = kv;
        }
        if (g >= 2 && g <= 11) {
            *(float4*)&Cu[y - 6][x0 - 4] = y2u;
            *(float4*)&Cv[y - 6][x0 - 4] = y2v;
        } else if (g == 1) {
            // x0 = 4: valid x = 6,7 -> j = 2,3 ; p = x - 4 = j
            Cu[y - 6][2] = el(y2u, 2); Cv[y - 6][2] = el(y2v, 2);
            Cu[y - 6][3] = el(y2u, 3); Cv[y - 6][3] = el(y2v, 3);
        } else if (g == 12) {
            // x0 = 48: valid x = 48,49 -> j = 0,1 ; p = 44 + j
            Cu[y - 6][44] = el(y2u, 0); Cv[y - 6][44] = el(y2v, 0);
            Cu[y - 6][45] = el(y2u, 1); Cv[y - 6][45] = el(y2v, 1);
        }
        if (y >= 12 && y < 44 && g >= 3 && g <= 10) {
            float4 tu = *(const float4*)&ACu[y - 12][x0 - 12];
            float4 tv = *(const float4*)&ACv[y - 12][x0 - 12];
            *(float4*)&ACu[y - 12][x0 - 12] = f4_fma(2.0f, kuq, tu);
            *(float4*)&ACv[y - 12][x0 - 12] = f4_fma(2.0f, kvq, tv);
        }
    }
    __syncthreads();

    // ---- stage 3: k3 over [9,47)^2 ; Y3 = u0 + 0.5 k3 -> B (reuse) ----
    for (int i = tid; i < 38 * 16; i += 256) {
        int rr = i >> 4, g = i & 15;
        int gc = min(max(g, 2), 11);
        int y  = rr + 9;
        int x0 = 4 * gc;
        float4 lu, cu, lv, cv;
        lap4(&Cu[0][0], y - 6, x0 - 4, CSTR, lu, cu);
        lap4(&Cv[0][0], y - 6, x0 - 4, CSTR, lv, cv);
        float4 au = *(const float4*)&Au[y][x0 + 4];
        float4 av = *(const float4*)&Av[y][x0 + 4];
        float4 y3u, y3v, kuq, kvq;
        #pragma unroll
        for (int j = 0; j < 4; ++j) {
            float u = el(cu, j), v = el(cv, j);
            float uv2 = u * v * v;
            float ku = fmaf(mu_u, el(lu, j), fmaf(NA, uv2, ff * (1.0f - u)));
            float kv = fmaf(mu_v, el(lv, j), fmaf(NB, uv2, -kpf * v));
            elr(y3u, j) = fmaf(0.5f, ku, el(au, j));
            elr(y3v, j) = fmaf(0.5f, kv, el(av, j));
            elr(kuq, j) = ku; elr(kvq, j) = kv;
        }
        if (g >= 3 && g <= 10) {
            *(float4*)&Bu[y - 3][x0] = y3u;
            *(float4*)&Bv[y - 3][x0] = y3v;
        } else if (g == 2) {
            // x0 = 8: valid x = 9,10,11 -> j = 1,2,3
            #pragma unroll
            for (int j = 1; j < 4; ++j) {
                Bu[y - 3][8 + j] = el(y3u, j); Bv[y - 3][8 + j] = el(y3v, j);
            }
        } else if (g == 11) {
            // x0 = 44: valid x = 44,45,46 -> j = 0,1,2
            #pragma unroll
            for (int j = 0; j < 3; ++j) {
                Bu[y - 3][44 + j] = el(y3u, j); Bv[y - 3][44 + j] = el(y3v, j);
            }
        }
        if (y >= 12 && y < 44 && g >= 3 && g <= 10) {
            float4 tu = *(const float4*)&ACu[y - 12][x0 - 12];
            float4 tv = *(const float4*)&ACv[y - 12][x0 - 12];
            *(float4*)&ACu[y - 12][x0 - 12] = f4_fma(2.0f, kuq, tu);
            *(float4*)&ACv[y - 12][x0 - 12] = f4_fma(2.0f, kvq, tv);
        }
    }
    __syncthreads();

    // ---- stage 4: k4 over [12,44)^2 ; write output ----
    for (int i = tid; i < 32 * 16; i += 256) {
        int rr = i >> 4, g = i & 15;
        int gc = min(max(g, 3), 10);
        int y  = rr + 12;
        int x0 = 4 * gc;
        float4 lu, cu, lv, cv;
        lap4(&Bu[0][0], y - 3, x0, BSTR, lu, cu);
        lap4(&Bv[0][0], y - 3, x0, BSTR, lv, cv);
        float4 au = *(const float4*)&Au[y][x0 + 4];
        float4 av = *(const float4*)&Av[y][x0 + 4];
        float4 acu = *(const float4*)&ACu[y - 12][x0 - 12];
        float4 acv = *(const float4*)&ACv[y - 12][x0 - 12];
        float4 ou, ov;
        #pragma unroll
        for (int j = 0; j < 4; ++j) {
            float u = el(cu, j), v = el(cv, j);
            float uv2 = u * v * v;
            float ku = fmaf(mu_u, el(lu, j), fmaf(NA, uv2, ff * (1.0f - u)));
            float kv = fmaf(mu_v, el(lv, j), fmaf(NB, uv2, -kpf * v));
            elr(ou, j) = fmaf(0.5f / 6.0f, el(acu, j) + ku, el(au, j));
            elr(ov, j) = fmaf(0.5f / 6.0f, el(acv, j) + kv, el(av, j));
        }
        if (g >= 3 && g <= 10) {
            int gy = blockIdx.y * TS + (y - 12);
            int gx = blockIdx.x * TS + (x0 - 12);
            size_t off = (size_t)gy * 1024 + gx;
            *(float4*)(out + baseU + off) = ou;
            *(float4*)(out + baseV + off) = ov;
        }
    }
}

extern "C" void kernel_launch(void* const* d_in, const int* in_sizes, int n_in,
                              void* d_out, int out_size, void* d_ws, size_t ws_size,
                              hipStream_t stream) {
    const float* h   = (const float*)d_in[0];
    const float* pCA = (const float*)d_in[1];
    const float* pCB = (const float*)d_in[2];
    const float* pNA = (const float*)d_in[3];
    const float* pNB = (const float*)d_in[4];
    const float* pf  = (const float*)d_in[5];
    const float* pk  = (const float*)d_in[6];
    float* out = (float*)d_out;

    dim3 grid(1024 / TS, 1024 / TS, 16);
    dim3 block(256);
    rcnn_rk4_fused<<<grid, block, 0, stream>>>(h, pCA, pCB, pNA, pNB, pf, pk, out);
}

// Round 4
// 120.840 us; speedup vs baseline: 3.5806x; 3.5806x over previous
//
#include <hip/hip_runtime.h>

// RK4 Gray-Scott via register-pipelined y-march.
// Block = 512 threads = full 1024-wide row (2 cols/thread, wrap &511).
// Marches a 64-row strip; vertical neighbors from register windows,
// horizontal +-3 neighbors via 4-slot rotating LDS row buffers per stage.
// Pipeline at step t (yL = Y0-12+t): push u0 row yL; k1 row yL-3;
// k2 row yL-6; k3 row yL-9; k4 + store row yL-12.

#define HROWS  64
#define NT     512
#define STEPS  (HROWS + 24)

#define W0 ((-980.0f / 1e-4f) / 180.0f)
#define W1 ((  270.0f / 1e-4f) / 180.0f)
#define W2 (( -27.0f / 1e-4f) / 180.0f)
#define W3 ((   2.0f / 1e-4f) / 180.0f)

struct Params { float mu_u, mu_v, NA, NB, ff, kpf; };

__device__ __forceinline__ void eval_stage(
    const float2* __restrict__ wu, const float2* __restrict__ wv,   // 7-row windows, center [3]
    const float2* __restrict__ lu, const float2* __restrict__ lv,   // LDS row (512 float2)
    int xm2, int xm1, int xp1, int xp2, const Params& P,
    float2& kU, float2& kV, float2& cU, float2& cV)
{
    float2 Lm2u = lu[xm2], Lm1u = lu[xm1], R1u = lu[xp1], R2u = lu[xp2];
    float2 Lm2v = lv[xm2], Lm1v = lv[xm1], R1v = lv[xp1], R2v = lv[xp2];
    cU = wu[3]; cV = wv[3];

    float vUa = fmaf(W1, wu[2].x + wu[4].x, fmaf(W2, wu[1].x + wu[5].x, W3 * (wu[0].x + wu[6].x)));
    float vUb = fmaf(W1, wu[2].y + wu[4].y, fmaf(W2, wu[1].y + wu[5].y, W3 * (wu[0].y + wu[6].y)));
    float vVa = fmaf(W1, wv[2].x + wv[4].x, fmaf(W2, wv[1].x + wv[5].x, W3 * (wv[0].x + wv[6].x)));
    float vVb = fmaf(W1, wv[2].y + wv[4].y, fmaf(W2, wv[1].y + wv[5].y, W3 * (wv[0].y + wv[6].y)));

    // point a = x0: -1=Lm1.y +1=c.y ; -2=Lm1.x +2=R1.x ; -3=Lm2.y +3=R1.y
    float hUa = fmaf(W1, Lm1u.y + cU.y, fmaf(W2, Lm1u.x + R1u.x, W3 * (Lm2u.y + R1u.y)));
    // point b = x0+1: -1=c.x +1=R1.x ; -2=Lm1.y +2=R1.y ; -3=Lm1.x +3=R2.x
    float hUb = fmaf(W1, cU.x + R1u.x, fmaf(W2, Lm1u.y + R1u.y, W3 * (Lm1u.x + R2u.x)));
    float hVa = fmaf(W1, Lm1v.y + cV.y, fmaf(W2, Lm1v.x + R1v.x, W3 * (Lm2v.y + R1v.y)));
    float hVb = fmaf(W1, cV.x + R1v.x, fmaf(W2, Lm1v.y + R1v.y, W3 * (Lm1v.x + R2v.x)));

    float lapUa = fmaf(W0, cU.x, hUa + vUa);
    float lapUb = fmaf(W0, cU.y, hUb + vUb);
    float lapVa = fmaf(W0, cV.x, hVa + vVa);
    float lapVb = fmaf(W0, cV.y, hVb + vVb);

    float uv2a = cU.x * cV.x * cV.x;
    float uv2b = cU.y * cV.y * cV.y;
    kU.x = fmaf(P.mu_u, lapUa, fmaf(P.NA, uv2a, P.ff * (1.0f - cU.x)));
    kU.y = fmaf(P.mu_u, lapUb, fmaf(P.NA, uv2b, P.ff * (1.0f - cU.y)));
    kV.x = fmaf(P.mu_v, lapVa, fmaf(P.NB, uv2a, -P.kpf * cV.x));
    kV.y = fmaf(P.mu_v, lapVb, fmaf(P.NB, uv2b, -P.kpf * cV.y));
}

#define SHIFT7(A) { A[6]=A[5]; A[5]=A[4]; A[4]=A[3]; A[3]=A[2]; A[2]=A[1]; A[1]=A[0]; }
#define SHIFT6(A) { A[5]=A[4]; A[4]=A[3]; A[3]=A[2]; A[2]=A[1]; A[1]=A[0]; }
#define SHIFT10(A){ A[9]=A[8]; A[8]=A[7]; A[7]=A[6]; A[6]=A[5]; A[5]=A[4]; A[4]=A[3]; A[3]=A[2]; A[2]=A[1]; A[1]=A[0]; }

__global__ __launch_bounds__(NT, 2) void rcnn_rk4_march(
    const float* __restrict__ h,
    const float* __restrict__ pCA, const float* __restrict__ pCB,
    const float* __restrict__ pNA, const float* __restrict__ pNB,
    const float* __restrict__ pf,  const float* __restrict__ pk,
    float* __restrict__ out)
{
    // stage buffers: 0=u0 1=Y1 2=Y2 3=Y3 ; 4 rotating row slots ; 2 channels
    __shared__ float2 S[4][4][2][512];

    const int tid = threadIdx.x;
    const int Y0  = blockIdx.x * HROWS;
    const int b   = blockIdx.z;

    Params P;
    P.NA = pNA[0]; P.NB = pNB[0];
    P.ff = pf[0];
    P.kpf = pk[0] + pf[0];
    P.mu_u = 4e-5f / (1.0f + expf(-pCA[0]));
    P.mu_v = 4e-5f / (1.0f + expf(-pCB[0]));

    const size_t baseU = (size_t)b * 2u * 1048576u;
    const size_t baseV = baseU + 1048576u;
    const float* hU = h + baseU + 2 * tid;
    const float* hV = h + baseV + 2 * tid;
    float* oU = out + baseU + 2 * tid;
    float* oV = out + baseV + 2 * tid;

    const int xm2 = (tid - 2) & 511;
    const int xm1 = (tid - 1) & 511;
    const int xp1 = (tid + 1) & 511;
    const int xp2 = (tid + 2) & 511;

    float2 u0u[7], u0v[7];        // rows yL .. yL-6
    float2 du[6],  dv[6];         // rows yL-7 .. yL-12
    float2 y1u[7], y1v[7];        // rows yL-3 .. yL-9
    float2 y2u[7], y2v[7];        // rows yL-6 .. yL-12
    float2 y3u[7], y3v[7];        // rows yL-9 .. yL-15
    float2 accu[10], accv[10];    // acc row yL-3-j at index j

    const float2 z = make_float2(0.0f, 0.0f);
    #pragma unroll
    for (int j = 0; j < 7; ++j) { u0u[j]=z; u0v[j]=z; y1u[j]=z; y1v[j]=z; y2u[j]=z; y2v[j]=z; y3u[j]=z; y3v[j]=z; }
    #pragma unroll
    for (int j = 0; j < 6; ++j) { du[j]=z; dv[j]=z; }
    #pragma unroll
    for (int j = 0; j < 10; ++j) { accu[j]=z; accv[j]=z; }

    // prefetch row Y0-12
    {
        int yl = (Y0 - 12) & 1023;
        float2 pu0 = *(const float2*)(hU + (size_t)yl * 1024);
        float2 pv0 = *(const float2*)(hV + (size_t)yl * 1024);
        u0u[0] = pu0; u0v[0] = pv0; // temp stash; real push happens in loop
    }
    float2 pu = u0u[0], pv = u0v[0];

    #pragma unroll 4
    for (int t = 0; t < STEPS; ++t) {
        // ---- consume prefetched u0 row yL = Y0-12+t ----
        SHIFT6(du); SHIFT6(dv);
        du[0] = u0u[6]; dv[0] = u0v[6];       // row (yL-1)-6 = yL-7
        SHIFT7(u0u); SHIFT7(u0v);
        u0u[0] = pu; u0v[0] = pv;
        S[0][t & 3][0][tid] = pu;
        S[0][t & 3][1][tid] = pv;
        SHIFT10(accu); SHIFT10(accv);

        // ---- prefetch next row ----
        {
            int yn = (Y0 - 12 + t + 1) & 1023;
            pu = *(const float2*)(hU + (size_t)yn * 1024);
            pv = *(const float2*)(hV + (size_t)yn * 1024);
        }

        // ---- k1: row yL-3 ----
        if (t >= 6) {
            float2 kU, kV, cU, cV;
            eval_stage(u0u, u0v, &S[0][(t + 1) & 3][0][0], &S[0][(t + 1) & 3][1][0],
                       xm2, xm1, xp1, xp2, P, kU, kV, cU, cV);
            float2 nY1u = make_float2(fmaf(0.25f, kU.x, cU.x), fmaf(0.25f, kU.y, cU.y));
            float2 nY1v = make_float2(fmaf(0.25f, kV.x, cV.x), fmaf(0.25f, kV.y, cV.y));
            SHIFT7(y1u); SHIFT7(y1v);
            y1u[0] = nY1u; y1v[0] = nY1v;
            S[1][(t + 1) & 3][0][tid] = nY1u;
            S[1][(t + 1) & 3][1][tid] = nY1v;
            accu[0] = kU; accv[0] = kV;
        }

        // ---- k2: row yL-6 ----
        if (t >= 12) {
            float2 kU, kV, cU, cV;
            eval_stage(y1u, y1v, &S[1][(t + 2) & 3][0][0], &S[1][(t + 2) & 3][1][0],
                       xm2, xm1, xp1, xp2, P, kU, kV, cU, cV);
            float2 nY2u = make_float2(fmaf(0.25f, kU.x, u0u[6].x), fmaf(0.25f, kU.y, u0u[6].y));
            float2 nY2v = make_float2(fmaf(0.25f, kV.x, u0v[6].x), fmaf(0.25f, kV.y, u0v[6].y));
            SHIFT7(y2u); SHIFT7(y2v);
            y2u[0] = nY2u; y2v[0] = nY2v;
            S[2][(t + 2) & 3][0][tid] = nY2u;
            S[2][(t + 2) & 3][1][tid] = nY2v;
            accu[3].x = fmaf(2.0f, kU.x, accu[3].x); accu[3].y = fmaf(2.0f, kU.y, accu[3].y);
            accv[3].x = fmaf(2.0f, kV.x, accv[3].x); accv[3].y = fmaf(2.0f, kV.y, accv[3].y);
        }

        // ---- k3: row yL-9 ----
        if (t >= 18) {
            float2 kU, kV, cU, cV;
            eval_stage(y2u, y2v, &S[2][(t + 3) & 3][0][0], &S[2][(t + 3) & 3][1][0],
                       xm2, xm1, xp1, xp2, P, kU, kV, cU, cV);
            float2 nY3u = make_float2(fmaf(0.5f, kU.x, du[2].x), fmaf(0.5f, kU.y, du[2].y));
            float2 nY3v = make_float2(fmaf(0.5f, kV.x, dv[2].x), fmaf(0.5f, kV.y, dv[2].y));
            SHIFT7(y3u); SHIFT7(y3v);
            y3u[0] = nY3u; y3v[0] = nY3v;
            S[3][(t + 3) & 3][0][tid] = nY3u;
            S[3][(t + 3) & 3][1][tid] = nY3v;
            accu[6].x = fmaf(2.0f, kU.x, accu[6].x); accu[6].y = fmaf(2.0f, kU.y, accu[6].y);
            accv[6].x = fmaf(2.0f, kV.x, accv[6].x); accv[6].y = fmaf(2.0f, kV.y, accv[6].y);
        }

        // ---- k4 + store: row yL-12 ----
        if (t >= 24) {
            float2 kU, kV, cU, cV;
            eval_stage(y3u, y3v, &S[3][t & 3][0][0], &S[3][t & 3][1][0],
                       xm2, xm1, xp1, xp2, P, kU, kV, cU, cV);
            float2 ou, ov;
            ou.x = fmaf(0.5f / 6.0f, accu[9].x + kU.x, du[5].x);
            ou.y = fmaf(0.5f / 6.0f, accu[9].y + kU.y, du[5].y);
            ov.x = fmaf(0.5f / 6.0f, accv[9].x + kV.x, dv[5].x);
            ov.y = fmaf(0.5f / 6.0f, accv[9].y + kV.y, dv[5].y);
            int yS = Y0 + t - 24;
            *(float2*)(oU + (size_t)yS * 1024) = ou;
            *(float2*)(oV + (size_t)yS * 1024) = ov;
        }

        // drain LDS writes only; keep the global prefetch in flight
        asm volatile("s_waitcnt lgkmcnt(0)" ::: "memory");
        __builtin_amdgcn_s_barrier();
        asm volatile("" ::: "memory");
    }
}

extern "C" void kernel_launch(void* const* d_in, const int* in_sizes, int n_in,
                              void* d_out, int out_size, void* d_ws, size_t ws_size,
                              hipStream_t stream) {
    const float* h   = (const float*)d_in[0];
    const float* pCA = (const float*)d_in[1];
    const float* pCB = (const float*)d_in[2];
    const float* pNA = (const float*)d_in[3];
    const float* pNB = (const float*)d_in[4];
    const float* pf  = (const float*)d_in[5];
    const float* pk  = (const float*)d_in[6];
    float* outp = (float*)d_out;

    dim3 grid(1024 / HROWS, 1, 16);   // 16 strips x 16 batches = 256 blocks
    dim3 block(NT);
    rcnn_rk4_march<<<grid, block, 0, stream>>>(h, pCA, pCB, pNA, pNB, pf, pk, outp);
}

// Round 5
// 100.973 us; speedup vs baseline: 4.2852x; 1.1968x over previous
//
#include <hip/hip_runtime.h>

// RK4 Gray-Scott, register-pipelined y-march, packed-f32 edition.
// Block = 512 threads = full 1024-wide row (2 cols/thread via f2, wrap &511).
// Vertical neighbors from per-thread register windows; horizontal +-3 via
// 4-slot rotating LDS row buffers (write at t, read at t+3, 1 barrier/step).
// RK sum reconstructed from Y windows: out = u0 + DT/6*(4Y1+8Y2+4Y3-16u0+k4).

typedef float f2 __attribute__((ext_vector_type(2)));

#define HROWS 64
#define NT    512
#define STEPS (HROWS + 24)

#define W0 ((-980.0f / 1e-4f) / 180.0f)
#define W1 ((  270.0f / 1e-4f) / 180.0f)
#define W2 (( -27.0f / 1e-4f) / 180.0f)
#define W3 ((   2.0f / 1e-4f) / 180.0f)

__device__ __forceinline__ f2 sp(float s) { f2 r; r.x = s; r.y = s; return r; }
__device__ __forceinline__ f2 pfma(float s, f2 a, f2 c) {
    return __builtin_elementwise_fma(sp(s), a, c);
}

// 13-pt Laplacian, packed over 2 columns. w = 7-row vertical window (center w[3]),
// L = LDS row of 512 f2. Point a = col 2*tid, b = col 2*tid+1.
__device__ __forceinline__ void evalp(const f2* __restrict__ w,
                                      const f2* __restrict__ L,
                                      int xm2, int xm1, int xp1, int xp2,
                                      f2& lap, f2& ctr)
{
    f2 Lm2 = L[xm2], Lm1 = L[xm1], R1 = L[xp1], R2 = L[xp2];
    ctr = w[3];
    f2 vp = pfma(W1, w[2] + w[4], pfma(W2, w[1] + w[5], sp(W3) * (w[0] + w[6])));
    f2 m1 = __builtin_shufflevector(Lm1, ctr, 1, 2);   // {a-1, b-1}
    f2 p1 = __builtin_shufflevector(ctr, R1, 1, 2);    // {a+1, b+1}
    f2 m3 = __builtin_shufflevector(Lm2, Lm1, 1, 2);   // {a-3, b-3}
    f2 p3 = __builtin_shufflevector(R1, R2, 1, 2);     // {a+3, b+3}
    f2 hp = pfma(W1, m1 + p1, pfma(W2, Lm1 + R1, sp(W3) * (m3 + p3)));
    lap = pfma(W0, ctr, hp + vp);
}

#define SH6(A)  { A[5]=A[4]; A[4]=A[3]; A[3]=A[2]; A[2]=A[1]; A[1]=A[0]; }
#define SH7(A)  { A[6]=A[5]; A[5]=A[4]; A[4]=A[3]; A[3]=A[2]; A[2]=A[1]; A[1]=A[0]; }
#define SH10(A) { A[9]=A[8]; A[8]=A[7]; A[7]=A[6]; A[6]=A[5]; A[5]=A[4]; A[4]=A[3]; A[3]=A[2]; A[2]=A[1]; A[1]=A[0]; }

__global__ __launch_bounds__(NT, 2) void rcnn_rk4_march(
    const float* __restrict__ h,
    const float* __restrict__ pCA, const float* __restrict__ pCB,
    const float* __restrict__ pNA, const float* __restrict__ pNB,
    const float* __restrict__ pf,  const float* __restrict__ pk,
    float* __restrict__ out)
{
    __shared__ f2 Su[4][4][NT], Sv[4][4][NT];   // [stage][slot][col] = 128 KiB

    const int tid = threadIdx.x;
    const int Y0  = blockIdx.x * HROWS;
    const int b   = blockIdx.z;

    const float NA = pNA[0], NB = pNB[0];
    const float ff = pf[0];
    const float kpf = pk[0] + pf[0];
    const float mu_u = 4e-5f / (1.0f + expf(-pCA[0]));
    const float mu_v = 4e-5f / (1.0f + expf(-pCB[0]));

    const size_t baseU = (size_t)b * 2u * 1048576u;
    const size_t baseV = baseU + 1048576u;
    const float* hU = h + baseU + 2 * tid;
    const float* hV = h + baseV + 2 * tid;
    float* oU = out + baseU + 2 * tid;
    float* oV = out + baseV + 2 * tid;

    const int xm2 = (tid - 2) & 511;
    const int xm1 = (tid - 1) & 511;
    const int xp1 = (tid + 1) & 511;
    const int xp2 = (tid + 2) & 511;

    // register state (post-shift at step t, yL = Y0-12+t):
    f2 u0u[7], u0v[7];     // u0 rows yL-j
    f2 du[6],  dv[6];      // u0 rows yL-7-j
    f2 y1u[10], y1v[10];   // Y1 rows yL-3-j
    f2 y2u[7],  y2v[7];    // Y2 rows yL-6-j
    f2 y3u[7],  y3v[7];    // Y3 rows yL-9-j

    const f2 z = sp(0.0f);
    #pragma unroll
    for (int j = 0; j < 7; ++j) { u0u[j]=z; u0v[j]=z; y2u[j]=z; y2v[j]=z; y3u[j]=z; y3v[j]=z; }
    #pragma unroll
    for (int j = 0; j < 6; ++j) { du[j]=z; dv[j]=z; }
    #pragma unroll
    for (int j = 0; j < 10; ++j) { y1u[j]=z; y1v[j]=z; }

    // prefetch row Y0-12
    f2 pu, pv;
    {
        int yl = (Y0 - 12) & 1023;
        pu = *(const f2*)(hU + (size_t)yl * 1024);
        pv = *(const f2*)(hV + (size_t)yl * 1024);
    }

#define STEP(D1, D2, D3, D4, tt)                                              \
  {                                                                           \
    const int t_ = (tt);                                                      \
    SH6(du); SH6(dv); du[0] = u0u[6]; dv[0] = u0v[6];                         \
    SH7(u0u); SH7(u0v); u0u[0] = pu; u0v[0] = pv;                             \
    Su[0][t_ & 3][tid] = pu; Sv[0][t_ & 3][tid] = pv;                         \
    {                                                                         \
      int yn = (Y0 - 12 + t_ + 1) & 1023;                                     \
      pu = *(const f2*)(hU + (size_t)yn * 1024);                              \
      pv = *(const f2*)(hV + (size_t)yn * 1024);                              \
    }                                                                         \
    if (D1) {                                                                 \
      f2 lU, cU1, lV, cV1;                                                    \
      evalp(u0u, &Su[0][(t_ + 1) & 3][0], xm2, xm1, xp1, xp2, lU, cU1);       \
      evalp(u0v, &Sv[0][(t_ + 1) & 3][0], xm2, xm1, xp1, xp2, lV, cV1);       \
      f2 uv2 = cU1 * cV1 * cV1;                                               \
      f2 kU = pfma(mu_u, lU, pfma(NA, uv2, pfma(-ff, cU1, sp(ff))));          \
      f2 kV = pfma(mu_v, lV, pfma(NB, uv2, sp(-kpf) * cV1));                  \
      f2 nu = pfma(0.25f, kU, cU1), nv = pfma(0.25f, kV, cV1);                \
      SH10(y1u); SH10(y1v); y1u[0] = nu; y1v[0] = nv;                         \
      Su[1][(t_ + 1) & 3][tid] = nu; Sv[1][(t_ + 1) & 3][tid] = nv;           \
    }                                                                         \
    if (D2) {                                                                 \
      f2 lU, cU2, lV, cV2;                                                    \
      evalp(y1u, &Su[1][(t_ + 2) & 3][0], xm2, xm1, xp1, xp2, lU, cU2);       \
      evalp(y1v, &Sv[1][(t_ + 2) & 3][0], xm2, xm1, xp1, xp2, lV, cV2);       \
      f2 uv2 = cU2 * cV2 * cV2;                                               \
      f2 kU = pfma(mu_u, lU, pfma(NA, uv2, pfma(-ff, cU2, sp(ff))));          \
      f2 kV = pfma(mu_v, lV, pfma(NB, uv2, sp(-kpf) * cV2));                  \
      f2 nu = pfma(0.25f, kU, u0u[6]), nv = pfma(0.25f, kV, u0v[6]);          \
      SH7(y2u); SH7(y2v); y2u[0] = nu; y2v[0] = nv;                           \
      Su[2][(t_ + 2) & 3][tid] = nu; Sv[2][(t_ + 2) & 3][tid] = nv;           \
    }                                                                         \
    if (D3) {                                                                 \
      f2 lU, cU3, lV, cV3;                                                    \
      evalp(y2u, &Su[2][(t_ + 3) & 3][0], xm2, xm1, xp1, xp2, lU, cU3);       \
      evalp(y2v, &Sv[2][(t_ + 3) & 3][0], xm2, xm1, xp1, xp2, lV, cV3);       \
      f2 uv2 = cU3 * cV3 * cV3;                                               \
      f2 kU = pfma(mu_u, lU, pfma(NA, uv2, pfma(-ff, cU3, sp(ff))));          \
      f2 kV = pfma(mu_v, lV, pfma(NB, uv2, sp(-kpf) * cV3));                  \
      f2 nu = pfma(0.5f, kU, du[2]), nv = pfma(0.5f, kV, dv[2]);              \
      SH7(y3u); SH7(y3v); y3u[0] = nu; y3v[0] = nv;                           \
      Su[3][(t_ + 3) & 3][tid] = nu; Sv[3][(t_ + 3) & 3][tid] = nv;           \
    }                                                                         \
    if (D4) {                                                                 \
      f2 lU, cU4, lV, cV4;                                                    \
      evalp(y3u, &Su[3][t_ & 3][0], xm2, xm1, xp1, xp2, lU, cU4);             \
      evalp(y3v, &Sv[3][t_ & 3][0], xm2, xm1, xp1, xp2, lV, cV4);             \
      f2 uv2 = cU4 * cV4 * cV4;                                               \
      f2 kU = pfma(mu_u, lU, pfma(NA, uv2, pfma(-ff, cU4, sp(ff))));          \
      f2 kV = pfma(mu_v, lV, pfma(NB, uv2, sp(-kpf) * cV4));                  \
      f2 aU = pfma(4.0f, y1u[9], kU);                                         \
      aU = pfma(8.0f, y2u[6], aU);                                            \
      aU = pfma(4.0f, cU4, aU);                                               \
      aU = pfma(-16.0f, du[5], aU);                                           \
      f2 aV = pfma(4.0f, y1v[9], kV);                                         \
      aV = pfma(8.0f, y2v[6], aV);                                            \
      aV = pfma(4.0f, cV4, aV);                                               \
      aV = pfma(-16.0f, dv[5], aV);                                           \
      f2 oUq = pfma(0.5f / 6.0f, aU, du[5]);                                  \
      f2 oVq = pfma(0.5f / 6.0f, aV, dv[5]);                                  \
      int yS = Y0 + t_ - 24;                                                  \
      *(f2*)(oU + (size_t)yS * 1024) = oUq;                                   \
      *(f2*)(oV + (size_t)yS * 1024) = oVq;                                   \
    }                                                                         \
    asm volatile("s_waitcnt lgkmcnt(0)" ::: "memory");                        \
    __builtin_amdgcn_s_barrier();                                             \
  }

    int t = 0;
    for (; t < 6;  ++t) STEP(0, 0, 0, 0, t)
    for (; t < 12; ++t) STEP(1, 0, 0, 0, t)
    for (; t < 18; ++t) STEP(1, 1, 0, 0, t)
    for (; t < 24; ++t) STEP(1, 1, 1, 0, t)
    #pragma unroll 4
    for (; t < STEPS; ++t) STEP(1, 1, 1, 1, t)
#undef STEP
}

extern "C" void kernel_launch(void* const* d_in, const int* in_sizes, int n_in,
                              void* d_out, int out_size, void* d_ws, size_t ws_size,
                              hipStream_t stream) {
    const float* h   = (const float*)d_in[0];
    const float* pCA = (const float*)d_in[1];
    const float* pCB = (const float*)d_in[2];
    const float* pNA = (const float*)d_in[3];
    const float* pNB = (const float*)d_in[4];
    const float* pf  = (const float*)d_in[5];
    const float* pk  = (const float*)d_in[6];
    float* outp = (float*)d_out;

    dim3 grid(1024 / HROWS, 1, 16);   // 16 strips x 16 batches = 256 blocks
    dim3 block(NT);
    rcnn_rk4_march<<<grid, block, 0, stream>>>(h, pCA, pCB, pNA, pNB, pf, pk, outp);
}